// Round 4
// baseline (576.058 us; speedup 1.0000x reference)
//
#include <hip/hip_runtime.h>

typedef unsigned short u16;
typedef unsigned int u32;
using bf16x8  = __attribute__((ext_vector_type(8))) __bf16;
using u16x8   = __attribute__((ext_vector_type(8), may_alias)) u16;
using u16x4   = __attribute__((ext_vector_type(4), may_alias)) u16;
using f32x4   = __attribute__((ext_vector_type(4))) float;
using f32x4_a = __attribute__((ext_vector_type(4), may_alias)) float;

#define DEV __device__ __forceinline__

constexpr int Bn = 4, Hn = 4, Nn = 2048, Mn = 2048, Dn = 64, DIMn = 256;
constexpr float SCALEc = 0.125f;   // 64^-0.5
constexpr float SHIFTc = 12.0f;    // fixed softmax shift (max logit ~6; overflow needs >100)
constexpr int LSTRIDE = 76;        // u16 stride for 64-m P tile; 38 dw, 38%32=6:
                                   // b64 store 1x/bank-pair, b128 read 2-way (free)

DEV float bf2f(u16 h) { u32 u = ((u32)h) << 16; return __builtin_bit_cast(float, u); }
DEV u16 f2bf(float f) {
    u32 u = __builtin_bit_cast(u32, f);
    u += 0x7fffu + ((u >> 16) & 1u);   // RNE
    return (u16)(u >> 16);
}
DEV bf16x8 ld8bf(const u16* p) {
    return __builtin_bit_cast(bf16x8, *reinterpret_cast<const u16x8*>(p));
}
DEV bf16x8 ld8f_bf(const float* p) {
    const f32x4 a = *reinterpret_cast<const f32x4_a*>(p);
    const f32x4 b = *reinterpret_cast<const f32x4_a*>(p + 4);
    u16x8 r;
    r[0] = f2bf(a[0]); r[1] = f2bf(a[1]); r[2] = f2bf(a[2]); r[3] = f2bf(a[3]);
    r[4] = f2bf(b[0]); r[5] = f2bf(b[1]); r[6] = f2bf(b[2]); r[7] = f2bf(b[3]);
    return __builtin_bit_cast(bf16x8, r);
}

// async global->LDS DMA, 16B per lane; dest = wave-uniform base + lane*16
typedef __attribute__((address_space(1))) const unsigned int as1_uint;
typedef __attribute__((address_space(3))) unsigned int as3_uint;
DEV void dma16(const float* g, float* l) {
    __builtin_amdgcn_global_load_lds((as1_uint*)g, (as3_uint*)l, 16, 0, 0);
}

// ---------------------------------------------------------------------------
// Fused QKV projection (one launch, 1024 blocks, 16-row tiles):
//  blocks [0,512):   Q = x_query @ Wq^T + bq  -> fp32 (B,H,N,D)
//  blocks [512,1024): K -> bf16 (B,H,M,D); V -> bf16 (B,H,D,M) transposed
// ---------------------------------------------------------------------------
__global__ __launch_bounds__(256) void qkv_kernel(
    const float* __restrict__ Xq, const float* __restrict__ Wq, const float* __restrict__ bq,
    const float* __restrict__ Xc, const float* __restrict__ Wk, const float* __restrict__ bk,
    const float* __restrict__ Wv, const float* __restrict__ bv,
    float* __restrict__ Q, u16* __restrict__ K, u16* __restrict__ V)
{
    const int wave = threadIdx.x >> 6, lane = threadIdx.x & 63;
    const int quad = lane >> 4, l16 = lane & 15;
    const int o0 = wave * 64;

    if (blockIdx.x < 512) {
        const int row0 = blockIdx.x * 16;
        const int b = row0 >> 11, n0 = row0 & 2047;
        f32x4 acc[4] = {};
        #pragma unroll
        for (int k0 = 0; k0 < 256; k0 += 32) {
            const bf16x8 af = ld8f_bf(Xq + (size_t)(row0 + l16) * DIMn + k0 + quad * 8);
            #pragma unroll
            for (int os = 0; os < 4; os++) {
                const bf16x8 wf = ld8f_bf(Wq + (size_t)(o0 + os * 16 + l16) * DIMn + k0 + quad * 8);
                acc[os] = __builtin_amdgcn_mfma_f32_16x16x32_bf16(af, wf, acc[os], 0, 0, 0);
            }
        }
        #pragma unroll
        for (int os = 0; os < 4; os++) {
            const int col = o0 + os * 16 + l16;
            const int h = col >> 6, d = col & 63;
            const float bb = bq[col];
            #pragma unroll
            for (int r = 0; r < 4; r++) {
                const int n = n0 + quad * 4 + r;
                Q[((size_t)(b * Hn + h) * Nn + n) * Dn + d] = acc[os][r] + bb;
            }
        }
    } else {
        const int row0 = (blockIdx.x - 512) * 16;
        const int b = row0 >> 11, n0 = row0 & 2047;
        f32x4 ack[4] = {};
        f32x4 acv[4] = {};
        #pragma unroll
        for (int k0 = 0; k0 < 256; k0 += 32) {
            const bf16x8 af = ld8f_bf(Xc + (size_t)(row0 + l16) * DIMn + k0 + quad * 8);
            #pragma unroll
            for (int os = 0; os < 4; os++) {
                const bf16x8 wkf = ld8f_bf(Wk + (size_t)(o0 + os * 16 + l16) * DIMn + k0 + quad * 8);
                ack[os] = __builtin_amdgcn_mfma_f32_16x16x32_bf16(af, wkf, ack[os], 0, 0, 0);
                const bf16x8 wvf = ld8f_bf(Wv + (size_t)(o0 + os * 16 + l16) * DIMn + k0 + quad * 8);
                acv[os] = __builtin_amdgcn_mfma_f32_16x16x32_bf16(wvf, af, acv[os], 0, 0, 0);
            }
        }
        #pragma unroll
        for (int os = 0; os < 4; os++) {
            const int col = o0 + os * 16 + l16;
            const int h = col >> 6, d = col & 63;
            const float bb = bk[col];
            #pragma unroll
            for (int r = 0; r < 4; r++) {
                const int m = n0 + quad * 4 + r;
                K[((size_t)(b * Hn + h) * Mn + m) * Dn + d] = f2bf(ack[os][r] + bb);
            }
        }
        #pragma unroll
        for (int os = 0; os < 4; os++)
            #pragma unroll
            for (int r = 0; r < 4; r++) {
                const int colf = o0 + os * 16 + quad * 4 + r;
                const int h = colf >> 6, d = colf & 63;
                const float bb = bv[colf];
                const int m = n0 + l16;
                V[((size_t)(b * Hn + h) * Dn + d) * Mn + m] = f2bf(acv[os][r] + bb);
            }
    }
}

// ---------------------------------------------------------------------------
// Flash attention, split-M, transposed score tiles (S^T = K Q^T).
// ONE WAVE per block (64 thr), 16 Q-rows, 64-m tiles.
// Grid (N/16, H, B*S). LDS 10624 B/block -> ~15 blocks/CU (vs 3 before).
//
// Concurrency design (the round-3 bug: geo DMA issued BEFORE PV's V loads
// meant the compiler's V-use vmcnt waits implicitly waited the OLDER geo DMA
// -- vmcnt retires in issue order -- serializing every tile behind ~900cy
// HBM latency; measured 1.14 TB/s = 1 outstanding load/wave):
//  - geo double-buffered in LDS, DMA'd 2 tiles ahead, issued at the very END
//    of the tile body (after all V loads) so no compiler wait chains on it.
//  - tile-top wait is vmcnt(6) = {next geo batch 4 + K-chain 2} allowed
//    outstanding; in-order retirement guarantees current geo landed. Never
//    vmcnt(0) in the loop.
//  - K fragments depth-1 register prefetch, chained across tiles.
// Fixed softmax shift -> split partials directly addable; oproj normalizes.
// ---------------------------------------------------------------------------
__global__ __launch_bounds__(64) void attn_kernel(
    const float* __restrict__ Q,    // (B,H,N,D) fp32
    const u16* __restrict__ K,      // (B,H,M,D) bf16
    const u16* __restrict__ V,      // (B,H,D,M) bf16
    const float* __restrict__ geo,  // (B,H,N,M) fp32
    float* __restrict__ Pnum,       // (S, B*N, 256) fp32 numerator partials
    float* __restrict__ Lsum,       // (S, B, H, N) fp32 denominator partials
    int S)
{
    __shared__ __align__(16) u16 plds[16 * LSTRIDE];     // 2432 B: P tile
    __shared__ __align__(16) float glds[2][4][256];      // 8192 B: geo dbuf

    const int h = blockIdx.y;
    const int b = blockIdx.z / S, split = blockIdx.z % S;
    const int lane = threadIdx.x & 63;
    const int quad = lane >> 4, l16 = lane & 15;
    const int nbase = blockIdx.x * 16;
    const int mlen = Mn / S, mbeg = split * mlen, mend = mbeg + mlen;

    const float* Qh = Q + ((size_t)(b * Hn + h) * Nn + nbase) * Dn;
    const u16*   Kh = K + (size_t)(b * Hn + h) * Mn * Dn;
    const u16*   Vh = V + (size_t)(b * Hn + h) * Dn * Mn;
    // per-lane geo source: row (nbase+l16), 16B chunk at col quad*4 within
    // each 16-col ms-block -> DMA dest lane*16 matches read-back below.
    const float* Gl = geo + ((size_t)(b * Hn + h) * Nn + nbase + l16) * (size_t)Mn + quad * 4;

    // Q^T B-fragments (hi/lo split for compensated QK^T)
    bf16x8 qh[2], ql[2];
    #pragma unroll
    for (int kh = 0; kh < 2; kh++) {
        const float* qp = Qh + (size_t)l16 * Dn + kh * 32 + quad * 8;
        const f32x4 a = *reinterpret_cast<const f32x4_a*>(qp);
        const f32x4 c = *reinterpret_cast<const f32x4_a*>(qp + 4);
        u16x8 hi, lo;
        #pragma unroll
        for (int j = 0; j < 4; j++) {
            hi[j] = f2bf(a[j]); lo[j] = f2bf(a[j] - bf2f(hi[j]));
            hi[4 + j] = f2bf(c[j]); lo[4 + j] = f2bf(c[j] - bf2f(hi[4 + j]));
        }
        qh[kh] = __builtin_bit_cast(bf16x8, hi);
        ql[kh] = __builtin_bit_cast(bf16x8, lo);
    }

    f32x4 oacc[4] = {};
    float lsum = 0.f;
    const u16* kbase = Kh + (size_t)l16 * Dn + quad * 8;
    const u16* vbase = Vh + (size_t)l16 * Mn + quad * 8;

    // prologue: DMA geo tiles 0 and 1 into buf0/buf1; first K fragment pair.
    #pragma unroll
    for (int ms = 0; ms < 4; ms++)
        dma16(Gl + mbeg + ms * 16, &glds[0][ms][0]);
    #pragma unroll
    for (int ms = 0; ms < 4; ms++)
        dma16(Gl + mbeg + 64 + ms * 16, &glds[1][ms][0]);
    bf16x8 kb0 = ld8bf(kbase + (size_t)mbeg * Dn);
    bf16x8 kb1 = ld8bf(kbase + (size_t)mbeg * Dn + 32);

    int buf = 0;
    for (int m0 = mbeg; m0 < mend; m0 += 64, buf ^= 1) {
        // wait until at most {next geo batch(4) + K chain(2)} outstanding:
        // in-order vmcnt retirement => this tile's geo has landed.
        asm volatile("s_waitcnt vmcnt(6)" ::: "memory");
        const float* gr = &glds[buf][0][0] + lane * 4;
        // --- QK^T + softmax numerator for 16n x 64m ---
        #pragma unroll
        for (int ms = 0; ms < 4; ms++) {
            int mb = m0 + (ms + 1) * 16;            // ms==3 -> next tile's ms=0
            if (mb > mend - 16) mb = mend - 16;     // clamp (uniform, cached reload)
            const u16* kp = kbase + (size_t)mb * Dn;
            const bf16x8 nk0 = ld8bf(kp);
            const bf16x8 nk1 = ld8bf(kp + 32);
            f32x4 s = {};
            __builtin_amdgcn_s_setprio(1);
            s = __builtin_amdgcn_mfma_f32_16x16x32_bf16(kb0, qh[0], s, 0, 0, 0);
            s = __builtin_amdgcn_mfma_f32_16x16x32_bf16(kb0, ql[0], s, 0, 0, 0);
            s = __builtin_amdgcn_mfma_f32_16x16x32_bf16(kb1, qh[1], s, 0, 0, 0);
            s = __builtin_amdgcn_mfma_f32_16x16x32_bf16(kb1, ql[1], s, 0, 0, 0);
            __builtin_amdgcn_s_setprio(0);
            const f32x4 g = *reinterpret_cast<const f32x4_a*>(gr + ms * 256);
            u16x4 pk;
            float ls = 0.f;
            #pragma unroll
            for (int r = 0; r < 4; r++) {
                const float p = __expf(fmaf(s[r], SCALEc, g[r]) - SHIFTc);
                ls += p;
                pk[r] = f2bf(p);
            }
            lsum += ls;
            *reinterpret_cast<u16x4*>(plds + l16 * LSTRIDE + ms * 16 + quad * 4) = pk;
            kb0 = nk0; kb1 = nk1;
        }
        // --- PV (2 kh-iters; V loads issue BEFORE the geo DMA below) ---
        #pragma unroll
        for (int kh = 0; kh < 2; kh++) {
            const bf16x8 pa = ld8bf(plds + l16 * LSTRIDE + kh * 32 + quad * 8);
            bf16x8 vb[4];
            #pragma unroll
            for (int ds = 0; ds < 4; ds++)
                vb[ds] = ld8bf(vbase + (size_t)(ds * 16) * Mn + m0 + kh * 32);
            __builtin_amdgcn_s_setprio(1);
            #pragma unroll
            for (int ds = 0; ds < 4; ds++)
                oacc[ds] = __builtin_amdgcn_mfma_f32_16x16x32_bf16(pa, vb[ds], oacc[ds], 0, 0, 0);
            __builtin_amdgcn_s_setprio(0);
        }
        // --- issue geo DMA for tile t+2 into the buffer consumed THIS tile.
        // Placed LAST so no compiler wait on K/V ever chains behind it.
        if (m0 + 128 < mend) {
            asm volatile("s_waitcnt lgkmcnt(0)" ::: "memory");  // geo reads done
            #pragma unroll
            for (int ms = 0; ms < 4; ms++)
                dma16(Gl + (m0 + 128) + ms * 16, &glds[buf][ms][0]);
        }
    }

    // reduce lsum across quads: all lanes end with full sum for col n=l16
    lsum += __shfl_xor(lsum, 16);
    lsum += __shfl_xor(lsum, 32);

    // write numerator partial (AO layout, per-split slab) and lsum partial
    float* PN = Pnum + (size_t)split * (Bn * (size_t)Nn * DIMn)
                     + ((size_t)b * Nn + nbase) * DIMn + h * Dn;
    #pragma unroll
    for (int r = 0; r < 4; r++)
        #pragma unroll
        for (int ds = 0; ds < 4; ds++)
            PN[(size_t)(quad * 4 + r) * DIMn + ds * 16 + l16] = oacc[ds][r];

    if (lane < 16)
        Lsum[(((size_t)split * Bn + b) * Hn + h) * Nn + nbase + l16] = lsum;
}

// ---------------------------------------------------------------------------
// Fused combine + output projection:
// AO[row][col] = (sum_s Pnum[s][row][col]) / (sum_s Lsum[s][h(col)][row-part])
// out = AO @ Wo^T + bo -> fp32 (B*N, 256), 16-row tiles, 512 blocks.
// ---------------------------------------------------------------------------
__global__ __launch_bounds__(256) void oproj_kernel(
    const float* __restrict__ Pnum, const float* __restrict__ Lsum,
    const float* __restrict__ W, const float* __restrict__ bias,
    float* __restrict__ out, int S)
{
    const int row0 = blockIdx.x * 16;
    const int wave = threadIdx.x >> 6, lane = threadIdx.x & 63;
    const int quad = lane >> 4, l16 = lane & 15;
    const int o0 = wave * 64;
    const size_t slab = (size_t)Bn * Nn * DIMn;

    // lane l16 owns A-row (row0+l16); denominators per head for that row
    const int arow = row0 + l16;
    const int b = arow >> 11, n = arow & 2047;
    float inv[4];
    #pragma unroll
    for (int hh = 0; hh < 4; hh++) {
        float l = 0.f;
        for (int s = 0; s < S; s++)
            l += Lsum[(((size_t)s * Bn + b) * Hn + hh) * Nn + n];
        inv[hh] = 1.0f / l;
    }

    f32x4 acc[4] = {};
    #pragma unroll
    for (int k0 = 0; k0 < 256; k0 += 32) {
        // combine Pnum slabs -> normalized bf16 A-fragment
        f32x4 a0 = {}, a1 = {};
        for (int s = 0; s < S; s++) {
            const float* p = Pnum + (size_t)s * slab + (size_t)arow * DIMn + k0 + quad * 8;
            a0 += *reinterpret_cast<const f32x4_a*>(p);
            a1 += *reinterpret_cast<const f32x4_a*>(p + 4);
        }
        const float iv = inv[(k0 + quad * 8) >> 6];
        u16x8 r;
        #pragma unroll
        for (int j = 0; j < 4; j++) {
            r[j]     = f2bf(a0[j] * iv);
            r[4 + j] = f2bf(a1[j] * iv);
        }
        const bf16x8 af = __builtin_bit_cast(bf16x8, r);
        #pragma unroll
        for (int os = 0; os < 4; os++) {
            const bf16x8 wf = ld8f_bf(W + (size_t)(o0 + os * 16 + l16) * DIMn + k0 + quad * 8);
            acc[os] = __builtin_amdgcn_mfma_f32_16x16x32_bf16(af, wf, acc[os], 0, 0, 0);
        }
    }
    #pragma unroll
    for (int os = 0; os < 4; os++) {
        const int col = o0 + os * 16 + l16;
        const float bb = bias[col];
        #pragma unroll
        for (int r = 0; r < 4; r++) {
            const int row = row0 + quad * 4 + r;
            out[(size_t)row * DIMn + col] = acc[os][r] + bb;
        }
    }
}

// ---------------------------------------------------------------------------
extern "C" void kernel_launch(void* const* d_in, const int* in_sizes, int n_in,
                              void* d_out, int out_size, void* d_ws, size_t ws_size,
                              hipStream_t stream) {
    const float* xq  = (const float*)d_in[0];
    const float* xc  = (const float*)d_in[1];
    const float* geo = (const float*)d_in[2];
    const float* Wq  = (const float*)d_in[3];
    const float* bq  = (const float*)d_in[4];
    const float* Wk  = (const float*)d_in[5];
    const float* bk  = (const float*)d_in[6];
    const float* Wv  = (const float*)d_in[7];
    const float* bv  = (const float*)d_in[8];
    const float* Wo  = (const float*)d_in[9];
    const float* bo  = (const float*)d_in[10];

    const int S = (ws_size >= (40ull << 20)) ? 2 : 1;

    char* ws = (char*)d_ws;
    float* Qw   = (float*)ws;                              // 8 MB fp32 (B,H,N,D)
    u16*   Kw   = (u16*)(ws + (8ull << 20));               // 4 MB bf16 (B,H,M,D)
    u16*   Vw   = (u16*)(ws + (12ull << 20));              // 4 MB bf16 (B,H,D,M)
    float* Pnum = (float*)(ws + (20ull << 20));            // S x 8 MB fp32
    float* Lsum = (float*)(ws + (20ull << 20) + (size_t)S * (8ull << 20));  // S x 128 KB

    qkv_kernel<<<1024, 256, 0, stream>>>(xq, Wq, bq, xc, Wk, bk, Wv, bv, Qw, Kw, Vw);
    attn_kernel<<<dim3(Nn / 16, Hn, Bn * S), 64, 0, stream>>>(Qw, Kw, Vw, geo, Pnum, Lsum, S);
    oproj_kernel<<<Bn * Nn / 16, 256, 0, stream>>>(Pnum, Lsum, Wo, bo, (float*)d_out, S);
}

// Round 5
// 515.465 us; speedup vs baseline: 1.1176x; 1.1176x over previous
//
#include <hip/hip_runtime.h>

typedef unsigned short u16;
typedef unsigned int u32;
using bf16x8  = __attribute__((ext_vector_type(8))) __bf16;
using u16x8   = __attribute__((ext_vector_type(8), may_alias)) u16;
using u16x4   = __attribute__((ext_vector_type(4), may_alias)) u16;
using f32x4   = __attribute__((ext_vector_type(4))) float;
using f32x4_a = __attribute__((ext_vector_type(4), may_alias)) float;

#define DEV __device__ __forceinline__

constexpr int Bn = 4, Hn = 4, Nn = 2048, Mn = 2048, Dn = 64, DIMn = 256;
constexpr float SCALEc = 0.125f;   // 64^-0.5
constexpr float SHIFTc = 12.0f;    // fixed softmax shift (max logit ~6; overflow needs >100)
constexpr int LSTRIDE = 76;        // u16 stride for 64-m P tile (conflict-light)

DEV float bf2f(u16 h) { u32 u = ((u32)h) << 16; return __builtin_bit_cast(float, u); }
DEV u16 f2bf(float f) {
    u32 u = __builtin_bit_cast(u32, f);
    u += 0x7fffu + ((u >> 16) & 1u);   // RNE
    return (u16)(u >> 16);
}
DEV bf16x8 ld8bf(const u16* p) {
    return __builtin_bit_cast(bf16x8, *reinterpret_cast<const u16x8*>(p));
}
DEV bf16x8 ld8f_bf(const float* p) {
    const f32x4 a = *reinterpret_cast<const f32x4_a*>(p);
    const f32x4 b = *reinterpret_cast<const f32x4_a*>(p + 4);
    u16x8 r;
    r[0] = f2bf(a[0]); r[1] = f2bf(a[1]); r[2] = f2bf(a[2]); r[3] = f2bf(a[3]);
    r[4] = f2bf(b[0]); r[5] = f2bf(b[1]); r[6] = f2bf(b[2]); r[7] = f2bf(b[3]);
    return __builtin_bit_cast(bf16x8, r);
}

// async global->LDS DMA, 16B per lane; LDS dest = wave-uniform base + lane*16.
typedef __attribute__((address_space(1))) const unsigned int as1_uint;
typedef __attribute__((address_space(3))) unsigned int as3_uint;
DEV void dma16(const void* g, void* l) {
    __builtin_amdgcn_global_load_lds((as1_uint*)g, (as3_uint*)l, 16, 0, 0);
}

// ---------------------------------------------------------------------------
// Weight prep: convert Wq/Wk/Wv/Wo fp32 -> bf16 once (saves the per-use
// fp32->bf16 VALU tax in qkv/oproj and halves W cache footprint).
// ---------------------------------------------------------------------------
__global__ __launch_bounds__(256) void wprep_kernel(
    const float* __restrict__ Wq, const float* __restrict__ Wk,
    const float* __restrict__ Wv, const float* __restrict__ Wo,
    u16* __restrict__ Wb)   // 4 x 65536 bf16: q,k,v,o
{
    const int idx = blockIdx.x * 256 + threadIdx.x;      // 0..32767
    const int m = idx >> 13;
    const int off = (idx & 8191) * 8;
    const float* src = (m == 0) ? Wq : (m == 1) ? Wk : (m == 2) ? Wv : Wo;
    const f32x4 a = *reinterpret_cast<const f32x4_a*>(src + off);
    const f32x4 c = *reinterpret_cast<const f32x4_a*>(src + off + 4);
    u16x8 o;
    #pragma unroll
    for (int j = 0; j < 4; j++) { o[j] = f2bf(a[j]); o[4 + j] = f2bf(c[j]); }
    *reinterpret_cast<u16x8*>(Wb + (size_t)m * 65536 + off) = o;
}

// ---------------------------------------------------------------------------
// Fused QKV projection (1024 blocks, 16-row tiles), bf16 weights:
//  blocks [0,512):   Q = x_query @ Wq^T + bq  -> fp32 (B,H,N,D)
//  blocks [512,1024): K -> bf16 (B,H,M,D); V -> bf16 (B,H,D,M) transposed
// ---------------------------------------------------------------------------
__global__ __launch_bounds__(256) void qkv_kernel(
    const float* __restrict__ Xq, const u16* __restrict__ Wqb, const float* __restrict__ bq,
    const float* __restrict__ Xc, const u16* __restrict__ Wkb, const float* __restrict__ bk,
    const u16* __restrict__ Wvb, const float* __restrict__ bv,
    float* __restrict__ Q, u16* __restrict__ K, u16* __restrict__ V)
{
    const int wave = threadIdx.x >> 6, lane = threadIdx.x & 63;
    const int quad = lane >> 4, l16 = lane & 15;
    const int o0 = wave * 64;

    if (blockIdx.x < 512) {
        const int row0 = blockIdx.x * 16;
        const int b = row0 >> 11, n0 = row0 & 2047;
        f32x4 acc[4] = {};
        #pragma unroll
        for (int k0 = 0; k0 < 256; k0 += 32) {
            const bf16x8 af = ld8f_bf(Xq + (size_t)(row0 + l16) * DIMn + k0 + quad * 8);
            #pragma unroll
            for (int os = 0; os < 4; os++) {
                const bf16x8 wf = ld8bf(Wqb + (size_t)(o0 + os * 16 + l16) * DIMn + k0 + quad * 8);
                acc[os] = __builtin_amdgcn_mfma_f32_16x16x32_bf16(af, wf, acc[os], 0, 0, 0);
            }
        }
        #pragma unroll
        for (int os = 0; os < 4; os++) {
            const int col = o0 + os * 16 + l16;
            const int h = col >> 6, d = col & 63;
            const float bb = bq[col];
            #pragma unroll
            for (int r = 0; r < 4; r++) {
                const int n = n0 + quad * 4 + r;
                Q[((size_t)(b * Hn + h) * Nn + n) * Dn + d] = acc[os][r] + bb;
            }
        }
    } else {
        const int row0 = (blockIdx.x - 512) * 16;
        const int b = row0 >> 11, n0 = row0 & 2047;
        f32x4 ack[4] = {};
        f32x4 acv[4] = {};
        #pragma unroll
        for (int k0 = 0; k0 < 256; k0 += 32) {
            const bf16x8 af = ld8f_bf(Xc + (size_t)(row0 + l16) * DIMn + k0 + quad * 8);
            #pragma unroll
            for (int os = 0; os < 4; os++) {
                const bf16x8 wkf = ld8bf(Wkb + (size_t)(o0 + os * 16 + l16) * DIMn + k0 + quad * 8);
                ack[os] = __builtin_amdgcn_mfma_f32_16x16x32_bf16(af, wkf, ack[os], 0, 0, 0);
                const bf16x8 wvf = ld8bf(Wvb + (size_t)(o0 + os * 16 + l16) * DIMn + k0 + quad * 8);
                acv[os] = __builtin_amdgcn_mfma_f32_16x16x32_bf16(wvf, af, acv[os], 0, 0, 0);
            }
        }
        #pragma unroll
        for (int os = 0; os < 4; os++) {
            const int col = o0 + os * 16 + l16;
            const int h = col >> 6, d = col & 63;
            const float bb = bk[col];
            #pragma unroll
            for (int r = 0; r < 4; r++) {
                const int m = n0 + quad * 4 + r;
                K[((size_t)(b * Hn + h) * Mn + m) * Dn + d] = f2bf(ack[os][r] + bb);
            }
        }
        #pragma unroll
        for (int os = 0; os < 4; os++)
            #pragma unroll
            for (int r = 0; r < 4; r++) {
                const int colf = o0 + os * 16 + quad * 4 + r;
                const int h = colf >> 6, d = colf & 63;
                const float bb = bv[colf];
                const int m = n0 + l16;
                V[((size_t)(b * Hn + h) * Dn + d) * Mn + m] = f2bf(acv[os][r] + bb);
            }
    }
}

// ---------------------------------------------------------------------------
// Flash attention, split-M, transposed score tiles (S^T = K Q^T).
// ONE WAVE per block, 16 Q-rows, 64-m tiles. Grid (N/16, H, B*S).
//
// Round-4 post-mortem: register-based prefetch is destroyed by the
// occupancy-targeting register allocator (VGPR capped 44..72 every round;
// loads sink to use sites; measured ~1 outstanding load/wave, 0.93 TB/s).
// Fix: encode the pipeline in MEMORY ops the allocator can't touch --
// ALL streams (geo+K+V) staged via global_load_lds (zero VGPR, vmcnt-
// tracked), double-buffered LDS, one batch = exactly 20 DMAs per tile:
//   geo 4 (HBM, issued first) + K 8 + V 8 (L2).
// Batch(t+2) issued at END of body t (into the buffer tile t just freed);
// tile-top wait = counted vmcnt(20) (drains batch(t), keeps batch(t+1) in
// flight). Never vmcnt(0) mid-loop. ~20KB in flight per wave continuously.
// K/V tiles are 64 rows x 128B, XOR-chunk swizzle applied on the GLOBAL
// source (linear DMA dest) and on the ds_read address -> conflict-free.
// Compute phase touches only LDS (ds_read, compiler-managed lgkm) + MFMA.
// LDS 43.4 KB -> 3 blocks/CU (intentional: latency hidden by DMA depth,
// not occupancy). No barriers (wave-private buffers).
// ---------------------------------------------------------------------------
__global__ __launch_bounds__(64, 1) void attn_kernel(
    const float* __restrict__ Q,    // (B,H,N,D) fp32
    const u16* __restrict__ K,      // (B,H,M,D) bf16
    const u16* __restrict__ V,      // (B,H,D,M) bf16
    const float* __restrict__ geo,  // (B,H,N,M) fp32
    float* __restrict__ Pnum,       // (S, B*N, 256) fp32 numerator partials
    float* __restrict__ Lsum,       // (S, B, H, N) fp32 denominator partials
    int S)
{
    __shared__ __align__(16) u16   Klds[2][4096];    // 16 KB: K tiles (64x128B, swz)
    __shared__ __align__(16) u16   Vlds[2][4096];    // 16 KB: V tiles (64x128B, swz)
    __shared__ __align__(16) float glds[2][4][256];  //  8 KB: geo tiles
    __shared__ __align__(16) u16   plds[16 * LSTRIDE]; // 2.4 KB: P tile

    const int h = blockIdx.y;
    const int b = blockIdx.z / S, split = blockIdx.z % S;
    const int lane = threadIdx.x & 63;
    const int quad = lane >> 4, l16 = lane & 15;
    const int r8 = lane >> 3, c8 = lane & 7;
    const int swz = c8 ^ r8;                 // source-chunk pre-swizzle
    const int nbase = blockIdx.x * 16;
    const int mlen = Mn / S, mbeg = split * mlen;
    const int nt = mlen / 64;

    const float* Qh = Q + ((size_t)(b * Hn + h) * Nn + nbase) * Dn;
    const u16*   Kh = K + (size_t)(b * Hn + h) * Mn * Dn;
    const u16*   Vh = V + (size_t)(b * Hn + h) * Dn * Mn;
    // per-lane DMA source bases (swizzled chunk within each 128B row)
    const u16*   Ksrc = Kh + (size_t)r8 * Dn + swz * 8;    // + m0*64 + i*512
    const u16*   Vsrc = Vh + (size_t)r8 * Mn + swz * 8;    // + m0 + i*8*Mn
    const float* Gsrc = geo + ((size_t)(b * Hn + h) * Nn + nbase + l16) * (size_t)Mn + quad * 4;

    // Q^T B-fragments (hi/lo split for compensated QK^T)
    bf16x8 qh[2], ql[2];
    #pragma unroll
    for (int kh = 0; kh < 2; kh++) {
        const float* qp = Qh + (size_t)l16 * Dn + kh * 32 + quad * 8;
        const f32x4 a = *reinterpret_cast<const f32x4_a*>(qp);
        const f32x4 c = *reinterpret_cast<const f32x4_a*>(qp + 4);
        u16x8 hi, lo;
        #pragma unroll
        for (int j = 0; j < 4; j++) {
            hi[j] = f2bf(a[j]); lo[j] = f2bf(a[j] - bf2f(hi[j]));
            hi[4 + j] = f2bf(c[j]); lo[4 + j] = f2bf(c[j] - bf2f(hi[4 + j]));
        }
        qh[kh] = __builtin_bit_cast(bf16x8, hi);
        ql[kh] = __builtin_bit_cast(bf16x8, lo);
    }

    // issue one tile's full DMA batch (exactly 20 ops; geo first: longest latency)
    auto issue = [&](int m0n, int bq) {
        float* gb = &glds[bq][0][0];
        #pragma unroll
        for (int ms = 0; ms < 4; ms++)
            dma16(Gsrc + m0n + ms * 16, gb + ms * 256);
        u16* kb = &Klds[bq][0];
        #pragma unroll
        for (int i = 0; i < 8; i++)
            dma16(Ksrc + (size_t)m0n * Dn + i * 512, kb + i * 512);
        u16* vbp = &Vlds[bq][0];
        #pragma unroll
        for (int i = 0; i < 8; i++)
            dma16(Vsrc + m0n + (size_t)i * 8 * Mn, vbp + i * 512);
    };

    f32x4 oacc[4] = {};
    float lsum = 0.f;
    const int lsw = l16 & 7;

    issue(mbeg, 0);
    issue(mbeg + 64, 1);

    for (int t = 0; t < nt; t++) {
        const int m0 = mbeg + t * 64;
        const int buf = t & 1;
        // drain batch(t); keep batch(t+1) (20 ops) in flight. asm "memory"
        // fences the ds_reads below from hoisting above the wait.
        if (t + 1 < nt) asm volatile("s_waitcnt vmcnt(20)" ::: "memory");
        else            asm volatile("s_waitcnt vmcnt(0)"  ::: "memory");

        const u16* kr = &Klds[buf][0];
        const u16* vr = &Vlds[buf][0];
        const float* gr = &glds[buf][0][0] + lane * 4;

        // --- QK^T + softmax numerator for 16n x 64m (all operands in LDS) ---
        #pragma unroll
        for (int ms = 0; ms < 4; ms++) {
            const int row = (ms * 16 + l16) * 64;
            const bf16x8 kb0 = ld8bf(kr + row + ((quad ^ lsw) << 3));
            const bf16x8 kb1 = ld8bf(kr + row + (((quad + 4) ^ lsw) << 3));
            f32x4 s = {};
            __builtin_amdgcn_s_setprio(1);
            s = __builtin_amdgcn_mfma_f32_16x16x32_bf16(kb0, qh[0], s, 0, 0, 0);
            s = __builtin_amdgcn_mfma_f32_16x16x32_bf16(kb0, ql[0], s, 0, 0, 0);
            s = __builtin_amdgcn_mfma_f32_16x16x32_bf16(kb1, qh[1], s, 0, 0, 0);
            s = __builtin_amdgcn_mfma_f32_16x16x32_bf16(kb1, ql[1], s, 0, 0, 0);
            __builtin_amdgcn_s_setprio(0);
            const f32x4 g = *reinterpret_cast<const f32x4_a*>(gr + ms * 256);
            u16x4 pk;
            float ls = 0.f;
            #pragma unroll
            for (int r = 0; r < 4; r++) {
                const float p = __expf(fmaf(s[r], SCALEc, g[r]) - SHIFTc);
                ls += p;
                pk[r] = f2bf(p);
            }
            lsum += ls;
            *reinterpret_cast<u16x4*>(plds + l16 * LSTRIDE + ms * 16 + quad * 4) = pk;
        }
        // --- PV (V from LDS, swizzled read) ---
        #pragma unroll
        for (int kh = 0; kh < 2; kh++) {
            const bf16x8 pa = ld8bf(plds + l16 * LSTRIDE + kh * 32 + quad * 8);
            bf16x8 vb[4];
            #pragma unroll
            for (int ds = 0; ds < 4; ds++)
                vb[ds] = ld8bf(vr + (ds * 16 + l16) * 64 + ((((kh << 2) + quad) ^ lsw) << 3));
            __builtin_amdgcn_s_setprio(1);
            #pragma unroll
            for (int ds = 0; ds < 4; ds++)
                oacc[ds] = __builtin_amdgcn_mfma_f32_16x16x32_bf16(pa, vb[ds], oacc[ds], 0, 0, 0);
            __builtin_amdgcn_s_setprio(0);
        }
        // issue batch(t+2) into the buffer tile t just finished reading.
        // Placed last: all of tile t's ds_reads have retired (lgkm waits
        // precede the MFMAs above), so the DMA writes can't race them.
        if (t + 2 < nt) issue(m0 + 128, buf);
    }

    // reduce lsum across quads: all lanes end with full sum for col n=l16
    lsum += __shfl_xor(lsum, 16);
    lsum += __shfl_xor(lsum, 32);

    // write numerator partial (AO layout, per-split slab) and lsum partial
    float* PN = Pnum + (size_t)split * (Bn * (size_t)Nn * DIMn)
                     + ((size_t)b * Nn + nbase) * DIMn + h * Dn;
    #pragma unroll
    for (int r = 0; r < 4; r++)
        #pragma unroll
        for (int ds = 0; ds < 4; ds++)
            PN[(size_t)(quad * 4 + r) * DIMn + ds * 16 + l16] = oacc[ds][r];

    if (lane < 16)
        Lsum[(((size_t)split * Bn + b) * Hn + h) * Nn + nbase + l16] = lsum;
}

// ---------------------------------------------------------------------------
// Fused combine + output projection (bf16 weights):
// AO[row][col] = (sum_s Pnum[s][row][col]) / (sum_s Lsum[s][h(col)][row])
// out = AO @ Wo^T + bo -> fp32 (B*N, 256), 16-row tiles, 512 blocks.
// ---------------------------------------------------------------------------
__global__ __launch_bounds__(256) void oproj_kernel(
    const float* __restrict__ Pnum, const float* __restrict__ Lsum,
    const u16* __restrict__ Wob, const float* __restrict__ bias,
    float* __restrict__ out, int S)
{
    const int row0 = blockIdx.x * 16;
    const int wave = threadIdx.x >> 6, lane = threadIdx.x & 63;
    const int quad = lane >> 4, l16 = lane & 15;
    const int o0 = wave * 64;
    const size_t slab = (size_t)Bn * Nn * DIMn;

    const int arow = row0 + l16;
    const int b = arow >> 11, n = arow & 2047;
    float inv[4];
    #pragma unroll
    for (int hh = 0; hh < 4; hh++) {
        float l = 0.f;
        for (int s = 0; s < S; s++)
            l += Lsum[(((size_t)s * Bn + b) * Hn + hh) * Nn + n];
        inv[hh] = 1.0f / l;
    }

    f32x4 acc[4] = {};
    #pragma unroll
    for (int k0 = 0; k0 < 256; k0 += 32) {
        f32x4 a0 = {}, a1 = {};
        for (int s = 0; s < S; s++) {
            const float* p = Pnum + (size_t)s * slab + (size_t)arow * DIMn + k0 + quad * 8;
            a0 += *reinterpret_cast<const f32x4_a*>(p);
            a1 += *reinterpret_cast<const f32x4_a*>(p + 4);
        }
        const float iv = inv[(k0 + quad * 8) >> 6];
        u16x8 r;
        #pragma unroll
        for (int j = 0; j < 4; j++) {
            r[j]     = f2bf(a0[j] * iv);
            r[4 + j] = f2bf(a1[j] * iv);
        }
        const bf16x8 af = __builtin_bit_cast(bf16x8, r);
        #pragma unroll
        for (int os = 0; os < 4; os++) {
            const bf16x8 wf = ld8bf(Wob + (size_t)(o0 + os * 16 + l16) * DIMn + k0 + quad * 8);
            acc[os] = __builtin_amdgcn_mfma_f32_16x16x32_bf16(af, wf, acc[os], 0, 0, 0);
        }
    }
    #pragma unroll
    for (int os = 0; os < 4; os++) {
        const int col = o0 + os * 16 + l16;
        const float bb = bias[col];
        #pragma unroll
        for (int r = 0; r < 4; r++) {
            const int row = row0 + quad * 4 + r;
            out[(size_t)row * DIMn + col] = acc[os][r] + bb;
        }
    }
}

// ---------------------------------------------------------------------------
extern "C" void kernel_launch(void* const* d_in, const int* in_sizes, int n_in,
                              void* d_out, int out_size, void* d_ws, size_t ws_size,
                              hipStream_t stream) {
    const float* xq  = (const float*)d_in[0];
    const float* xc  = (const float*)d_in[1];
    const float* geo = (const float*)d_in[2];
    const float* Wq  = (const float*)d_in[3];
    const float* bq  = (const float*)d_in[4];
    const float* Wk  = (const float*)d_in[5];
    const float* bk  = (const float*)d_in[6];
    const float* Wv  = (const float*)d_in[7];
    const float* bv  = (const float*)d_in[8];
    const float* Wo  = (const float*)d_in[9];
    const float* bo  = (const float*)d_in[10];

    const int S = (ws_size >= (40ull << 20)) ? 2 : 1;

    char* ws = (char*)d_ws;
    float* Qw   = (float*)ws;                              // 8 MB fp32 (B,H,N,D)
    u16*   Kw   = (u16*)(ws + (8ull << 20));               // 4 MB bf16 (B,H,M,D)
    u16*   Vw   = (u16*)(ws + (12ull << 20));              // 4 MB bf16 (B,H,D,M)
    u16*   Wb   = (u16*)(ws + (16ull << 20));              // 512 KB bf16 weights x4
    float* Pnum = (float*)(ws + (20ull << 20));            // S x 8 MB fp32
    float* Lsum = (float*)(ws + (20ull << 20) + (size_t)S * (8ull << 20));  // S x 128 KB

    wprep_kernel<<<128, 256, 0, stream>>>(Wq, Wk, Wv, Wo, Wb);
    qkv_kernel<<<1024, 256, 0, stream>>>(xq, Wb, bq, xc, Wb + 65536, bk,
                                         Wb + 131072, bv, Qw, Kw, Vw);
    attn_kernel<<<dim3(Nn / 16, Hn, Bn * S), 64, 0, stream>>>(Qw, Kw, Vw, geo, Pnum, Lsum, S);
    oproj_kernel<<<Bn * Nn / 16, 256, 0, stream>>>(Pnum, Lsum, Wb + 196608, bo, (float*)d_out, S);
}